// Round 12
// baseline (370.232 us; speedup 1.0000x reference)
//
#include <hip/hip_runtime.h>
#include <hip/hip_bf16.h>

typedef unsigned short u16;
typedef unsigned long long u64;
using bf16x8 = __attribute__((ext_vector_type(8))) short;
using f32x4v = __attribute__((ext_vector_type(4))) float;
typedef float v2f __attribute__((ext_vector_type(2)));

#define HC 256     // H*C
#define CDIM 64

__device__ __forceinline__ float b2f(u16 u){
  union { unsigned int i; float f; } c; c.i = ((unsigned)u) << 16; return c.f;
}
__device__ __forceinline__ u16 f2b(float f){
  union { float f; unsigned int i; } c; c.f = f;
  unsigned int x = c.i;
  return (u16)((x + 0x7FFFu + ((x >> 16) & 1u)) >> 16);   // RNE
}
// flag-aware external load: isbf=1 -> data is bf16, else fp32
__device__ __forceinline__ float ldf(const void* p, size_t i, int isbf){
  return isbf ? b2f(((const u16*)p)[i]) : ((const float*)p)[i];
}
__device__ __forceinline__ float sel4(float4 v, int h){ return h==0?v.x:(h==1?v.y:(h==2?v.z:v.w)); }
__device__ __forceinline__ float lrelu(float v){ return v>0.f ? v : 0.2f*v; }

// async global->LDS copy, 16B per lane; lds dest = wave-uniform base + lane*16
__device__ __forceinline__ void glds16(const void* g, void* l){
  __builtin_amdgcn_global_load_lds(
      (const __attribute__((address_space(1))) unsigned int*)g,
      (__attribute__((address_space(3))) unsigned int*)l, 16, 0, 0);
}

__device__ __forceinline__ float4 wave_max4(float4 m){
  #pragma unroll
  for(int o=32;o>0;o>>=1){
    m.x=fmaxf(m.x,__shfl_xor(m.x,o));
    m.y=fmaxf(m.y,__shfl_xor(m.y,o));
    m.z=fmaxf(m.z,__shfl_xor(m.z,o));
    m.w=fmaxf(m.w,__shfl_xor(m.w,o));
  }
  return m;
}
__device__ __forceinline__ float4 wave_sum4(float4 m){
  #pragma unroll
  for(int o=32;o>0;o>>=1){
    m.x+=__shfl_xor(m.x,o);
    m.y+=__shfl_xor(m.y,o);
    m.z+=__shfl_xor(m.z,o);
    m.w+=__shfl_xor(m.w,o);
  }
  return m;
}

// ---------------- hist + (block 0) dtype detection ----------------
__global__ void k_hist(const int* __restrict__ dst, int E, int N, int* __restrict__ deg,
                       const u16* __restrict__ x, int nelem, int* __restrict__ flag){
  int e = blockIdx.x*256 + threadIdx.x;
  if (e < E){
    int d = dst[e];
    if ((unsigned)d < (unsigned)N) atomicAdd(&deg[d], 1);
  }
  if (blockIdx.x == 0){
    __shared__ int bad;
    if (threadIdx.x==0) bad = 0;
    __syncthreads();
    int n = nelem < 8192 ? nelem : 8192;
    int localbad = 0;
    for (int i=threadIdx.x; i<n; i+=256){
      int ex = (x[i] >> 7) & 0xFF;
      if (ex >= 140) localbad++;
    }
    if (localbad) atomicAdd(&bad, 1);
    __syncthreads();
    if (threadIdx.x==0) *flag = (bad==0) ? 1 : 0;   // 1 = bf16, 0 = fp32
  }
}

// ---------------- 2-kernel scan (deg -> per-block exclusive rowptr + scanned bsums) ----------------
// consumers add bsums[i>>8] (scan3 folded into scatter / soft_agg)
__global__ void k_scan1(const int* __restrict__ in, int* __restrict__ out, int* __restrict__ bsums, int n){
  __shared__ int s[256];
  int t = threadIdx.x;
  int i = blockIdx.x*256 + t;
  int v = (i<n)? in[i] : 0;
  s[t]=v; __syncthreads();
  for(int off=1; off<256; off<<=1){
    int tv = (t>=off)? s[t-off] : 0;
    __syncthreads();
    s[t]+=tv; __syncthreads();
  }
  if (i<n) out[i] = s[t]-v;            // exclusive within block
  if (t==255) bsums[blockIdx.x] = s[255];
}

__global__ void k_scan2(int* __restrict__ bsums, int nb){
  __shared__ int s[256];
  int t=threadIdx.x;
  int v=(t<nb)? bsums[t]:0;
  s[t]=v; __syncthreads();
  for(int off=1; off<256; off<<=1){
    int tv=(t>=off)? s[t-off]:0;
    __syncthreads();
    s[t]+=tv; __syncthreads();
  }
  if (t<nb) bsums[t]=s[t]-v;
}

// ---------------- scatter: one packed nontemporal 8B store per edge ----------------
// epk[p] = (ew_bits << 32) | src ; p = rowptr[d] + bsums[d>>8] + cursor++
__global__ void k_scatter(const int* __restrict__ src, const int* __restrict__ dst,
                          const void* __restrict__ ew, int E, int N,
                          const int* __restrict__ rowptr, const int* __restrict__ bsums,
                          int* __restrict__ cursor, u64* __restrict__ epk,
                          const int* __restrict__ flagp){
  int e = blockIdx.x*256+threadIdx.x;
  if (e>=E) return;
  int bf = *flagp;
  int d = dst[e];
  if ((unsigned)d >= (unsigned)N) return;
  int p = rowptr[d] + bsums[d>>8] + atomicAdd(&cursor[d],1);
  int s = src[e];
  if ((unsigned)s >= (unsigned)N) s = 0;
  u64 v = ((u64)__float_as_uint(ldf(ew, e, bf)) << 32) | (unsigned)s;
  __builtin_nontemporal_store(v, &epk[p]);
}

// ---------------- combined prep: Bt1, Bt2, ce(both layers) ----------------
__global__ void k_prep(const void* __restrict__ W1, const void* __restrict__ W2,
                       const void* __restrict__ We1, const void* __restrict__ ae1,
                       const void* __restrict__ We2, const void* __restrict__ ae2,
                       u16* __restrict__ Bt1, u16* __restrict__ Bt2, float* __restrict__ ce,
                       const int* __restrict__ flagp){
  int bf = *flagp;
  int b = blockIdx.x, t = threadIdx.x;
  if (b < 128){
    Bt1[(size_t)t*128 + b] = f2b(ldf(W1, (size_t)b*HC + t, bf));
  } else if (b < 384){
    int k = b - 128;
    Bt2[(size_t)t*256 + k] = f2b(ldf(W2, (size_t)k*HC + t, bf));
  } else {
    float p1 = ldf(We1, t, bf)*ldf(ae1, t, bf);
    float p2 = ldf(We2, t, bf)*ldf(ae2, t, bf);
    #pragma unroll
    for(int o=32;o>0;o>>=1){ p1+=__shfl_xor(p1,o); p2+=__shfl_xor(p2,o); }
    if((t&63)==0){ ce[t>>6]=p1; ce[4+(t>>6)]=p2; }
  }
}

// ---------------- MFMA GEMM: C[m][0:256] = A[m][:]*B, tile 64x256, BK=64 ----------------
// BK=64: 32 MFMA per barrier pair (2x fewer barriers than BK=32).
// B (and internal-bf16 A) staged via global_load_lds. Epilogue: C via LDS bounce +
// shuffle-free per-row attention dots a_s/a_d.
__global__ __launch_bounds__(256) void k_gemm_mfma(
    const void* __restrict__ A, int a_ext, const u16* __restrict__ Bt,
    u16* __restrict__ C, const void* __restrict__ att_s, const void* __restrict__ att_d,
    float* __restrict__ a_s, float* __restrict__ a_d,
    int M, int K, const int* __restrict__ flagp)
{
  __shared__ u16 sh[4096 + 16384];     // 40 KB: As 64x64 + Bs 256x64; epilogue reuses as 64x264 C tile (33.8 KB)
  __shared__ float att_sh[512];        // [0:256) att_s (f32), [256:512) att_d
  u16* As = sh;
  u16* Bs = sh + 4096;
  int bf = *flagp;
  int a_bf = a_ext ? bf : 1;
  int tid = threadIdx.x;
  int lane = tid & 63, w = tid >> 6;
  int quad = lane >> 4, ln = lane & 15;
  int m0 = blockIdx.x * 64;

  att_sh[tid]       = ldf(att_s, tid, bf);
  att_sh[256 + tid] = ldf(att_d, tid, bf);

  f32x4v acc[4][4] = {};
  for (int k0 = 0; k0 < K; k0 += 64){
    // ---- stage A tile 64x64 (8 KB) ----
    if (!a_ext){
      // internal bf16 A: async DMA; tail over-read lands in adjacent ws arrays (rows discarded)
      #pragma unroll
      for (int j=0;j<2;j++){
        int chunk = w*2 + j;                       // 8 rows per 1 KB chunk
        int r = m0 + chunk*8 + (lane>>3);
        const u16* gA = (const u16*)A + (size_t)r*K + k0 + (lane&7)*8;
        glds16(gA, (char*)As + chunk*1024);
      }
    } else {
      // external A: VGPR staging w/ bounds guard + optional fp32->bf16 convert.
      // thread t covers As[t*16 .. t*16+16): row=t>>2, k-ofs=(t&3)*16
      int r = m0 + (tid>>2);
      int kk = (tid&3)*16;
      uint4 p0, p1;
      if (r < M){
        size_t base = (size_t)r*K + k0 + kk;
        if (a_bf){
          p0 = *(const uint4*)((const u16*)A + base);
          p1 = *(const uint4*)((const u16*)A + base + 8);
        } else {
          const float* Af = (const float*)A + base;
          float4 f0=*(const float4*)Af, f1=*(const float4*)(Af+4);
          float4 f2=*(const float4*)(Af+8), f3=*(const float4*)(Af+12);
          p0 = make_uint4((unsigned)f2b(f0.x)|((unsigned)f2b(f0.y)<<16),
                          (unsigned)f2b(f0.z)|((unsigned)f2b(f0.w)<<16),
                          (unsigned)f2b(f1.x)|((unsigned)f2b(f1.y)<<16),
                          (unsigned)f2b(f1.z)|((unsigned)f2b(f1.w)<<16));
          p1 = make_uint4((unsigned)f2b(f2.x)|((unsigned)f2b(f2.y)<<16),
                          (unsigned)f2b(f2.z)|((unsigned)f2b(f2.w)<<16),
                          (unsigned)f2b(f3.x)|((unsigned)f2b(f3.y)<<16),
                          (unsigned)f2b(f3.z)|((unsigned)f2b(f3.w)<<16));
        }
      } else { p0 = make_uint4(0,0,0,0); p1 = p0; }
      *(uint4*)&As[(size_t)tid*16]     = p0;
      *(uint4*)&As[(size_t)tid*16 + 8] = p1;
    }
    // ---- stage B tile 256x64 (32 KB) via async DMA ([n][k] bf16, in-bounds) ----
    #pragma unroll
    for (int i=0;i<8;i++){
      int chunk = w*8 + i;                         // 8 rows per 1 KB chunk
      int n = chunk*8 + (lane>>3);
      const u16* gB = Bt + (size_t)n*K + k0 + (lane&7)*8;
      glds16(gB, (char*)Bs + chunk*1024);
    }
    __syncthreads();
    #pragma unroll
    for (int half=0; half<2; half++){
      int ko = half*32 + quad*8;
      bf16x8 af[4], bfr[4];
      #pragma unroll
      for (int mi=0;mi<4;mi++) af[mi] = *(const bf16x8*)&As[(mi*16+ln)*64 + ko];
      #pragma unroll
      for (int nj=0;nj<4;nj++) bfr[nj] = *(const bf16x8*)&Bs[(w*64+nj*16+ln)*64 + ko];
      #pragma unroll
      for (int mi=0;mi<4;mi++)
        #pragma unroll
        for (int nj=0;nj<4;nj++)
          acc[mi][nj] = __builtin_amdgcn_mfma_f32_16x16x32_bf16(af[mi], bfr[nj], acc[mi][nj], 0,0,0);
    }
    __syncthreads();
  }
  // dump accumulators to LDS (C/D layout: row=quad*4+reg, col=lane&15), packed converts
  #pragma unroll
  for (int mi=0;mi<4;mi++)
    #pragma unroll
    for (int nj=0;nj<4;nj++){
      union { __hip_bfloat162 h2; u16 u[2]; } cv0, cv1;
      cv0.h2 = __float22bfloat162_rn(make_float2(acc[mi][nj][0], acc[mi][nj][1]));
      cv1.h2 = __float22bfloat162_rn(make_float2(acc[mi][nj][2], acc[mi][nj][3]));
      int col = w*64 + nj*16 + ln;
      int rbase = mi*16 + quad*4;
      sh[(rbase+0)*264 + col] = cv0.u[0];
      sh[(rbase+1)*264 + col] = cv0.u[1];
      sh[(rbase+2)*264 + col] = cv1.u[0];
      sh[(rbase+3)*264 + col] = cv1.u[1];
    }
  __syncthreads();
  // coalesced bulk store of the 64x256 bf16 tile
  #pragma unroll
  for (int j=0;j<8;j++){
    int idx = j*256 + tid;
    int r = idx >> 5, gq = idx & 31;
    if (m0 + r < M)
      *(uint4*)(C + (size_t)(m0+r)*HC + gq*8) = *(const uint4*)&sh[r*264 + gq*8];
  }
  // per-row attention dots, shuffle-free: lane l -> row w*16+(l&15), head l>>4.
  {
    int r  = w*16 + ln;
    int hh = quad;
    const u16* crow = &sh[r*264 + hh*64];
    const float* asv = &att_sh[hh*64];
    const float* adv = &att_sh[256 + hh*64];
    float ps = 0.f, pd = 0.f;
    #pragma unroll
    for (int cb=0; cb<64; cb+=8){
      ushort4 ua = *(const ushort4*)&crow[cb];
      ushort4 ub = *(const ushort4*)&crow[cb+4];
      float4 sa = *(const float4*)&asv[cb];
      float4 sb = *(const float4*)&asv[cb+4];
      float4 da = *(const float4*)&adv[cb];
      float4 db = *(const float4*)&adv[cb+4];
      float c0=b2f(ua.x), c1=b2f(ua.y), c2=b2f(ua.z), c3=b2f(ua.w);
      float c4=b2f(ub.x), c5=b2f(ub.y), c6=b2f(ub.z), c7=b2f(ub.w);
      ps += c0*sa.x + c1*sa.y + c2*sa.z + c3*sa.w + c4*sb.x + c5*sb.y + c6*sb.z + c7*sb.w;
      pd += c0*da.x + c1*da.y + c2*da.z + c3*da.w + c4*db.x + c5*db.y + c6*db.z + c7*db.w;
    }
    if (m0 + r < M){
      a_s[(size_t)(m0+r)*4 + hh] = ps;
      a_d[(size_t)(m0+r)*4 + hh] = pd;
    }
  }
}

// ---------------- fused segment softmax + aggregation + layer epilogue ----------------
// one wave per destination node, zero LDS. deg<=64: lane p owns edge p; weights are
// pre-transposed into tw[]; inner accumulate in float2 vectors (v_pk_fma_f32).
__global__ __launch_bounds__(256) void k_soft_agg(
    const u16* __restrict__ xs, const int* __restrict__ rowptr, const int* __restrict__ bsums,
    const int* __restrict__ deg, const u64* __restrict__ epk,
    const float* __restrict__ a_s, const float* __restrict__ a_d, const float* __restrict__ ce4,
    const void* __restrict__ bias, void* __restrict__ outp, int N, int layer,
    const int* __restrict__ flagp){
  int bf = *flagp;
  int lane = threadIdx.x & 63;
  int w = threadIdx.x >> 6;
  int n = (blockIdx.x<<2) + w;
  if (n >= N) return;
  int row = rowptr[n] + bsums[n>>8];
  int dg = deg[n];
  float4 ad = *(const float4*)&a_d[(size_t)n*4];
  float4 ce = *(const float4*)ce4;
  int h = lane >> 4;
  float4 acc = make_float4(0.f,0.f,0.f,0.f);
  if (dg > 0){
    if (dg <= 64){
      // --- softmax state fully in registers: lane p owns edge p ---
      int   s_reg = 0;
      float4 ar = make_float4(-1e30f,-1e30f,-1e30f,-1e30f);
      if (lane < dg){
        u64 pk = epk[row + lane];
        int s = (int)(unsigned)(pk & 0xFFFFFFFFull);
        if ((unsigned)s >= (unsigned)N) s = 0;
        s_reg = s;
        float wv = __uint_as_float((unsigned)(pk >> 32));
        float4 as = *(const float4*)&a_s[(size_t)s*4];
        ar.x = lrelu(as.x+ad.x+wv*ce.x);
        ar.y = lrelu(as.y+ad.y+wv*ce.y);
        ar.z = lrelu(as.z+ad.z+wv*ce.z);
        ar.w = lrelu(as.w+ad.w+wv*ce.w);
      }
      float4 m = wave_max4(ar);
      float4 ex = make_float4(0.f,0.f,0.f,0.f);
      if (lane < dg){
        ex.x=__expf(ar.x-m.x); ex.y=__expf(ar.y-m.y);
        ex.z=__expf(ar.z-m.z); ex.w=__expf(ar.w-m.w);
      }
      float4 ss = wave_sum4(ex);
      float4 wgt;
      wgt.x = ex.x/(ss.x+1e-16f); wgt.y = ex.y/(ss.y+1e-16f);
      wgt.z = ex.z/(ss.z+1e-16f); wgt.w = ex.w/(ss.w+1e-16f);
      // --- transpose weights: tw[j] lane l = head-(l>>4) weight of edge j*16+(l&15) ---
      float tw[4];
      #pragma unroll
      for (int j=0;j<4;j++){
        if (j*16 < dg){
          int srcl = j*16 + (lane & 15);
          float c0=__shfl(wgt.x,srcl), c1=__shfl(wgt.y,srcl);
          float c2=__shfl(wgt.z,srcl), c3=__shfl(wgt.w,srcl);
          tw[j] = (h==0)?c0:((h==1)?c1:((h==2)?c2:c3));
        } else tw[j] = 0.f;
      }
      int ibase = lane & 48;   // h*16
      v2f a01 = {0.f,0.f}, a23 = {0.f,0.f};
      // --- aggregation: 16-edge segments, unroll 4; 1 readlane + 1 shfl per edge ---
      #pragma unroll
      for (int j=0;j<4;j++){
        int j0 = j*16;
        if (j0 >= dg) break;
        float twj = tw[j];
        int cnt = dg - j0; if (cnt > 16) cnt = 16;
        int t = 0;
        for (; t+4<=cnt; t+=4){
          int e = j0 + t;
          int s0=__builtin_amdgcn_readlane(s_reg,e+0);
          int s1=__builtin_amdgcn_readlane(s_reg,e+1);
          int s2=__builtin_amdgcn_readlane(s_reg,e+2);
          int s3=__builtin_amdgcn_readlane(s_reg,e+3);
          float w0=__shfl(twj, ibase+t+0);
          float w1=__shfl(twj, ibase+t+1);
          float w2=__shfl(twj, ibase+t+2);
          float w3=__shfl(twj, ibase+t+3);
          uint2 x0 = *(const uint2*)&xs[(size_t)s0*HC + lane*4];
          uint2 x1 = *(const uint2*)&xs[(size_t)s1*HC + lane*4];
          uint2 x2 = *(const uint2*)&xs[(size_t)s2*HC + lane*4];
          uint2 x3 = *(const uint2*)&xs[(size_t)s3*HC + lane*4];
          v2f f;
          f = (v2f){__uint_as_float(x0.x<<16), __uint_as_float(x0.x&0xFFFF0000u)}; a01 += f*w0;
          f = (v2f){__uint_as_float(x0.y<<16), __uint_as_float(x0.y&0xFFFF0000u)}; a23 += f*w0;
          f = (v2f){__uint_as_float(x1.x<<16), __uint_as_float(x1.x&0xFFFF0000u)}; a01 += f*w1;
          f = (v2f){__uint_as_float(x1.y<<16), __uint_as_float(x1.y&0xFFFF0000u)}; a23 += f*w1;
          f = (v2f){__uint_as_float(x2.x<<16), __uint_as_float(x2.x&0xFFFF0000u)}; a01 += f*w2;
          f = (v2f){__uint_as_float(x2.y<<16), __uint_as_float(x2.y&0xFFFF0000u)}; a23 += f*w2;
          f = (v2f){__uint_as_float(x3.x<<16), __uint_as_float(x3.x&0xFFFF0000u)}; a01 += f*w3;
          f = (v2f){__uint_as_float(x3.y<<16), __uint_as_float(x3.y&0xFFFF0000u)}; a23 += f*w3;
        }
        for (; t<cnt; t++){
          int s0=__builtin_amdgcn_readlane(s_reg,j0+t);
          float w0=__shfl(twj, ibase+t);
          uint2 x0 = *(const uint2*)&xs[(size_t)s0*HC + lane*4];
          v2f f;
          f = (v2f){__uint_as_float(x0.x<<16), __uint_as_float(x0.x&0xFFFF0000u)}; a01 += f*w0;
          f = (v2f){__uint_as_float(x0.y<<16), __uint_as_float(x0.y&0xFFFF0000u)}; a23 += f*w0;
        }
      }
      acc.x = a01.x; acc.y = a01.y; acc.z = a23.x; acc.w = a23.y;
    } else {
      // fallback: recompute (no LDS); statistically never taken at E/N=16
      float4 m = make_float4(-1e30f,-1e30f,-1e30f,-1e30f);
      for (int p=lane;p<dg;p+=64){
        u64 pk = epk[row+p];
        int s = (int)(unsigned)(pk & 0xFFFFFFFFull);
        if ((unsigned)s >= (unsigned)N) s = 0;
        float wv = __uint_as_float((unsigned)(pk >> 32));
        float4 as = *(const float4*)&a_s[(size_t)s*4];
        m.x=fmaxf(m.x, lrelu(as.x+ad.x+wv*ce.x));
        m.y=fmaxf(m.y, lrelu(as.y+ad.y+wv*ce.y));
        m.z=fmaxf(m.z, lrelu(as.z+ad.z+wv*ce.z));
        m.w=fmaxf(m.w, lrelu(as.w+ad.w+wv*ce.w));
      }
      m = wave_max4(m);
      float4 ss = make_float4(0.f,0.f,0.f,0.f);
      for (int p=lane;p<dg;p+=64){
        u64 pk = epk[row+p];
        int s = (int)(unsigned)(pk & 0xFFFFFFFFull);
        if ((unsigned)s >= (unsigned)N) s = 0;
        float wv = __uint_as_float((unsigned)(pk >> 32));
        float4 as = *(const float4*)&a_s[(size_t)s*4];
        ss.x+=__expf(lrelu(as.x+ad.x+wv*ce.x)-m.x);
        ss.y+=__expf(lrelu(as.y+ad.y+wv*ce.y)-m.y);
        ss.z+=__expf(lrelu(as.z+ad.z+wv*ce.z)-m.z);
        ss.w+=__expf(lrelu(as.w+ad.w+wv*ce.w)-m.w);
      }
      ss = wave_sum4(ss);
      float rsel=1.f/(sel4(ss,h)+1e-16f), mh=sel4(m,h), adh=sel4(ad,h), ceh=sel4(ce,h);
      for (int e=0;e<dg;e++){
        u64 pk = epk[row+e];
        int s = (int)(unsigned)(pk & 0xFFFFFFFFull);
        if ((unsigned)s >= (unsigned)N) s = 0;
        float wv = __uint_as_float((unsigned)(pk >> 32));
        float arv = lrelu(a_s[(size_t)s*4+h]+adh+wv*ceh);
        float wgt = __expf(arv-mh)*rsel;
        ushort4 xv4 = *(const ushort4*)&xs[(size_t)s*HC + lane*4];
        acc.x+=wgt*b2f(xv4.x); acc.y+=wgt*b2f(xv4.y);
        acc.z+=wgt*b2f(xv4.z); acc.w+=wgt*b2f(xv4.w);
      }
    }
  }
  if (layer==1){
    // h = relu(l2norm(acc + b1)) -> bf16
    float4 v;
    v.x = acc.x + ldf(bias, lane*4+0, bf);
    v.y = acc.y + ldf(bias, lane*4+1, bf);
    v.z = acc.z + ldf(bias, lane*4+2, bf);
    v.w = acc.w + ldf(bias, lane*4+3, bf);
    float ss = v.x*v.x+v.y*v.y+v.z*v.z+v.w*v.w;
    #pragma unroll
    for(int o=32;o>0;o>>=1) ss += __shfl_xor(ss,o);
    float inv = 1.f/fmaxf(sqrtf(ss), 1e-12f);
    ushort4 o4;
    o4.x = f2b(fmaxf(v.x*inv,0.f)); o4.y = f2b(fmaxf(v.y*inv,0.f));
    o4.z = f2b(fmaxf(v.z*inv,0.f)); o4.w = f2b(fmaxf(v.w*inv,0.f));
    *(ushort4*)((u16*)outp + (size_t)n*HC + lane*4) = o4;
  } else {
    // mean over heads + b2 -> final output
    float4 s = acc;
    #pragma unroll
    for (int o=16;o<=32;o<<=1){
      s.x+=__shfl_xor(s.x,o); s.y+=__shfl_xor(s.y,o);
      s.z+=__shfl_xor(s.z,o); s.w+=__shfl_xor(s.w,o);
    }
    if (lane < 16){
      float4 v;
      v.x = 0.25f*s.x + ldf(bias, lane*4+0, bf);
      v.y = 0.25f*s.y + ldf(bias, lane*4+1, bf);
      v.z = 0.25f*s.z + ldf(bias, lane*4+2, bf);
      v.w = 0.25f*s.w + ldf(bias, lane*4+3, bf);
      if (bf){
        ushort4 o4; o4.x=f2b(v.x); o4.y=f2b(v.y); o4.z=f2b(v.z); o4.w=f2b(v.w);
        *(ushort4*)((u16*)outp + (size_t)n*CDIM + lane*4) = o4;
      } else {
        *(float4*)((float*)outp + (size_t)n*CDIM + lane*4) = v;
      }
    }
  }
}

extern "C" void kernel_launch(void* const* d_in, const int* in_sizes, int n_in,
                              void* d_out, int out_size, void* d_ws, size_t ws_size,
                              hipStream_t stream){
  const void* x_in = d_in[0];
  const int* eidx  = (const int*)d_in[1];
  const void* ew   = d_in[2];
  const void* W1   = d_in[3];
  const void* as1  = d_in[4];
  const void* ad1  = d_in[5];
  const void* We1  = d_in[6];
  const void* ae1  = d_in[7];
  const void* b1   = d_in[8];
  const void* W2   = d_in[9];
  const void* as2  = d_in[10];
  const void* ad2  = d_in[11];
  const void* We2  = d_in[12];
  const void* ae2  = d_in[13];
  const void* b2   = d_in[14];

  int N = in_sizes[0]/128;
  int E = in_sizes[2];
  const int* src = eidx;
  const int* dst = eidx + E;

  char* w = (char*)d_ws;
  auto alloc = [&](size_t bytes)->char*{ char* p=w; w += (bytes+255)/256*256; return p; };
  int*   flag  = (int*)alloc(256);
  u16*   xs    = (u16*)alloc((size_t)N*HC*2);   // bf16 feature buffer A
  u16*   agg   = (u16*)alloc((size_t)N*HC*2);   // bf16 feature buffer B (h); GEMM2 tail over-reads into a_s (safe)
  float* a_s   = (float*)alloc((size_t)N*4*4);
  float* a_d   = (float*)alloc((size_t)N*4*4);
  int*   deg   = (int*)alloc((size_t)N*4);
  int*   cursor= (int*)alloc((size_t)N*4);      // adjacent to deg: single memset covers both
  int*   rowptr= (int*)alloc((size_t)N*4);
  int*   bsums = (int*)alloc(256*4);
  u64*   epk   = (u64*)alloc((size_t)E*8);      // packed (ew<<32 | src) per edge
  float* ce    = (float*)alloc(256);            // [0:4)=layer1, [4:8)=layer2
  u16*   Bt1   = (u16*)alloc((size_t)HC*128*2); // W1^T bf16 [256][128]
  u16*   Bt2   = (u16*)alloc((size_t)HC*HC*2);  // W2^T bf16 [256][256]

  (void)hipMemsetAsync(deg, 0, (size_t)((char*)cursor - (char*)deg) + (size_t)N*4, stream);

  int eb = (E+255)/256;
  int nb = (N+255)/256;
  k_hist<<<eb,256,0,stream>>>(dst, E, N, deg, (const u16*)x_in, in_sizes[0], flag);
  k_scan1<<<nb,256,0,stream>>>(deg, rowptr, bsums, N);
  k_scan2<<<1,256,0,stream>>>(bsums, nb);
  k_scatter<<<eb,256,0,stream>>>(src, dst, ew, E, N, rowptr, bsums, cursor, epk, flag);
  k_prep<<<385,256,0,stream>>>(W1, W2, We1, ae1, We2, ae2, Bt1, Bt2, ce, flag);

  int gemmBlocks = (N+63)/64;
  int nwb = (N+3)/4;   // 4 node-waves per block

  // ---- layer 1 ----
  k_gemm_mfma<<<gemmBlocks,256,0,stream>>>(x_in, 1, Bt1, xs, as1, ad1, a_s, a_d, N, 128, flag);
  k_soft_agg<<<nwb,256,0,stream>>>(xs, rowptr, bsums, deg, epk, a_s, a_d, ce, b1, agg, N, 1, flag);

  // ---- layer 2 ----
  k_gemm_mfma<<<gemmBlocks,256,0,stream>>>(agg, 0, Bt2, xs, as2, ad2, a_s, a_d, N, 256, flag);
  k_soft_agg<<<nwb,256,0,stream>>>(xs, rowptr, bsums, deg, epk, a_s, a_d, ce+4, b2, d_out, N, 2, flag);
}

// Round 13
// 339.804 us; speedup vs baseline: 1.0895x; 1.0895x over previous
//
#include <hip/hip_runtime.h>
#include <hip/hip_bf16.h>

typedef unsigned short u16;
typedef unsigned long long u64;
using bf16x8 = __attribute__((ext_vector_type(8))) short;
using f32x4v = __attribute__((ext_vector_type(4))) float;
typedef float v2f __attribute__((ext_vector_type(2)));

#define HC 256     // H*C
#define CDIM 64

__device__ __forceinline__ float b2f(u16 u){
  union { unsigned int i; float f; } c; c.i = ((unsigned)u) << 16; return c.f;
}
__device__ __forceinline__ u16 f2b(float f){
  union { float f; unsigned int i; } c; c.f = f;
  unsigned int x = c.i;
  return (u16)((x + 0x7FFFu + ((x >> 16) & 1u)) >> 16);   // RNE
}
// flag-aware external load: isbf=1 -> data is bf16, else fp32
__device__ __forceinline__ float ldf(const void* p, size_t i, int isbf){
  return isbf ? b2f(((const u16*)p)[i]) : ((const float*)p)[i];
}
__device__ __forceinline__ float sel4(float4 v, int h){ return h==0?v.x:(h==1?v.y:(h==2?v.z:v.w)); }
__device__ __forceinline__ float lrelu(float v){ return v>0.f ? v : 0.2f*v; }

// async global->LDS copy, 16B per lane; lds dest = wave-uniform base + lane*16
__device__ __forceinline__ void glds16(const void* g, void* l){
  __builtin_amdgcn_global_load_lds(
      (const __attribute__((address_space(1))) unsigned int*)g,
      (__attribute__((address_space(3))) unsigned int*)l, 16, 0, 0);
}

__device__ __forceinline__ float4 wave_max4(float4 m){
  #pragma unroll
  for(int o=32;o>0;o>>=1){
    m.x=fmaxf(m.x,__shfl_xor(m.x,o));
    m.y=fmaxf(m.y,__shfl_xor(m.y,o));
    m.z=fmaxf(m.z,__shfl_xor(m.z,o));
    m.w=fmaxf(m.w,__shfl_xor(m.w,o));
  }
  return m;
}
__device__ __forceinline__ float4 wave_sum4(float4 m){
  #pragma unroll
  for(int o=32;o>0;o>>=1){
    m.x+=__shfl_xor(m.x,o);
    m.y+=__shfl_xor(m.y,o);
    m.z+=__shfl_xor(m.z,o);
    m.w+=__shfl_xor(m.w,o);
  }
  return m;
}

// ---------------- hist (+rank capture) + (block 0) dtype detection ----------------
// rank[e] = this edge's arrival index within its dst bucket (atomicAdd return).
__global__ void k_hist(const int* __restrict__ dst, int E, int N, int* __restrict__ deg,
                       int* __restrict__ rank,
                       const u16* __restrict__ x, int nelem, int* __restrict__ flag){
  int e = blockIdx.x*256 + threadIdx.x;
  if (e < E){
    int d = dst[e];
    if ((unsigned)d < (unsigned)N) rank[e] = atomicAdd(&deg[d], 1);
  }
  if (blockIdx.x == 0){
    __shared__ int bad;
    if (threadIdx.x==0) bad = 0;
    __syncthreads();
    int n = nelem < 8192 ? nelem : 8192;
    int localbad = 0;
    for (int i=threadIdx.x; i<n; i+=256){
      int ex = (x[i] >> 7) & 0xFF;
      if (ex >= 140) localbad++;
    }
    if (localbad) atomicAdd(&bad, 1);
    __syncthreads();
    if (threadIdx.x==0) *flag = (bad==0) ? 1 : 0;   // 1 = bf16, 0 = fp32
  }
}

// ---------------- 2-kernel scan (deg -> per-block exclusive rowptr + scanned bsums) ----------------
// consumers add bsums[i>>8]
__global__ void k_scan1(const int* __restrict__ in, int* __restrict__ out, int* __restrict__ bsums, int n){
  __shared__ int s[256];
  int t = threadIdx.x;
  int i = blockIdx.x*256 + t;
  int v = (i<n)? in[i] : 0;
  s[t]=v; __syncthreads();
  for(int off=1; off<256; off<<=1){
    int tv = (t>=off)? s[t-off] : 0;
    __syncthreads();
    s[t]+=tv; __syncthreads();
  }
  if (i<n) out[i] = s[t]-v;            // exclusive within block
  if (t==255) bsums[blockIdx.x] = s[255];
}

__global__ void k_scan2(int* __restrict__ bsums, int nb){
  __shared__ int s[256];
  int t=threadIdx.x;
  int v=(t<nb)? bsums[t]:0;
  s[t]=v; __syncthreads();
  for(int off=1; off<256; off<<=1){
    int tv=(t>=off)? s[t-off]:0;
    __syncthreads();
    s[t]+=tv; __syncthreads();
  }
  if (t<nb) bsums[t]=s[t]-v;
}

// ---------------- scatter: ATOMIC-FREE; one packed nontemporal 8B store per edge ----------------
// epk[p] = (ew_bits << 32) | src ; p = rowptr[d] + bsums[d>>8] + rank[e]
__global__ void k_scatter(const int* __restrict__ src, const int* __restrict__ dst,
                          const void* __restrict__ ew, int E, int N,
                          const int* __restrict__ rowptr, const int* __restrict__ bsums,
                          const int* __restrict__ rank, u64* __restrict__ epk,
                          const int* __restrict__ flagp){
  int e = blockIdx.x*256+threadIdx.x;
  if (e>=E) return;
  int bf = *flagp;
  int d = dst[e];
  if ((unsigned)d >= (unsigned)N) return;
  int p = rowptr[d] + bsums[d>>8] + rank[e];
  int s = src[e];
  if ((unsigned)s >= (unsigned)N) s = 0;
  u64 v = ((u64)__float_as_uint(ldf(ew, e, bf)) << 32) | (unsigned)s;
  __builtin_nontemporal_store(v, &epk[p]);
}

// ---------------- combined prep: Bt1, Bt2, ce(both layers) ----------------
__global__ void k_prep(const void* __restrict__ W1, const void* __restrict__ W2,
                       const void* __restrict__ We1, const void* __restrict__ ae1,
                       const void* __restrict__ We2, const void* __restrict__ ae2,
                       u16* __restrict__ Bt1, u16* __restrict__ Bt2, float* __restrict__ ce,
                       const int* __restrict__ flagp){
  int bf = *flagp;
  int b = blockIdx.x, t = threadIdx.x;
  if (b < 128){
    Bt1[(size_t)t*128 + b] = f2b(ldf(W1, (size_t)b*HC + t, bf));
  } else if (b < 384){
    int k = b - 128;
    Bt2[(size_t)t*256 + k] = f2b(ldf(W2, (size_t)k*HC + t, bf));
  } else {
    float p1 = ldf(We1, t, bf)*ldf(ae1, t, bf);
    float p2 = ldf(We2, t, bf)*ldf(ae2, t, bf);
    #pragma unroll
    for(int o=32;o>0;o>>=1){ p1+=__shfl_xor(p1,o); p2+=__shfl_xor(p2,o); }
    if((t&63)==0){ ce[t>>6]=p1; ce[4+(t>>6)]=p2; }
  }
}

// ---------------- MFMA GEMM: C[m][0:256] = A[m][:]*B, tile 64x256, BK=32 ----------------
// B staged with global_load_lds (async DMA); A likewise when bf16-internal.
// Also computes per-row attention dots a_s/a_d in the epilogue (shuffle-free).
__global__ __launch_bounds__(256) void k_gemm_mfma(
    const void* __restrict__ A, int a_ext, const u16* __restrict__ Bt,
    u16* __restrict__ C, const void* __restrict__ att_s, const void* __restrict__ att_d,
    float* __restrict__ a_s, float* __restrict__ a_d,
    int M, int K, const int* __restrict__ flagp)
{
  __shared__ u16 sh[64*264];           // 33 KB; K-loop: [As 2048][Bs 8192]; epilogue: 64x264 C tile
  __shared__ float att_sh[512];        // [0:256) att_s (f32), [256:512) att_d
  u16* As = sh;
  u16* Bs = sh + 2048;
  int bf = *flagp;
  int a_bf = a_ext ? bf : 1;
  int tid = threadIdx.x;
  int lane = tid & 63, w = tid >> 6;
  int quad = lane >> 4, ln = lane & 15;
  int m0 = blockIdx.x * 64;

  att_sh[tid]       = ldf(att_s, tid, bf);
  att_sh[256 + tid] = ldf(att_d, tid, bf);

  f32x4v acc[4][4] = {};
  for (int k0 = 0; k0 < K; k0 += 32){
    // stage A tile 64x32
    if (!a_ext){
      // internal bf16 A: async DMA. Tail over-read lands in adjacent ws arrays (rows discarded).
      const u16* gA = (const u16*)A + (size_t)(m0 + (tid>>2))*K + k0 + (size_t)(tid&3)*8;
      glds16(gA, (char*)As + (size_t)w*1024);
    } else {
      int m = tid >> 2, g = tid & 3;
      int r = m0 + m;
      uint4 pack;
      if (r < M){
        size_t base = (size_t)r*K + k0 + g*8;
        if (a_bf){
          pack = *(const uint4*)((const u16*)A + base);
        } else {
          const float* Af = (const float*)A + base;
          float4 f0 = *(const float4*)Af;
          float4 f1 = *(const float4*)(Af+4);
          unsigned a0 = (unsigned)f2b(f0.x) | ((unsigned)f2b(f0.y)<<16);
          unsigned a1 = (unsigned)f2b(f0.z) | ((unsigned)f2b(f0.w)<<16);
          unsigned a2 = (unsigned)f2b(f1.x) | ((unsigned)f2b(f1.y)<<16);
          unsigned a3 = (unsigned)f2b(f1.z) | ((unsigned)f2b(f1.w)<<16);
          pack = make_uint4(a0,a1,a2,a3);
        }
      } else pack = make_uint4(0,0,0,0);
      ((uint4*)As)[tid] = pack;
    }
    // stage B tile 256x32 via async DMA ([n][k] bf16, always in-bounds)
    #pragma unroll
    for (int i=0;i<4;i++){
      const u16* gB = Bt + (size_t)(i*64 + (tid>>2))*K + k0 + (size_t)(tid&3)*8;
      glds16(gB, (char*)Bs + (size_t)i*4096 + (size_t)w*1024);
    }
    __syncthreads();
    bf16x8 af[4], bfr[4];
    #pragma unroll
    for (int mi=0;mi<4;mi++) af[mi] = *(const bf16x8*)&As[(mi*16+ln)*32 + quad*8];
    #pragma unroll
    for (int nj=0;nj<4;nj++) bfr[nj] = *(const bf16x8*)&Bs[((size_t)w*64+nj*16+ln)*32 + quad*8];
    #pragma unroll
    for (int mi=0;mi<4;mi++)
      #pragma unroll
      for (int nj=0;nj<4;nj++)
        acc[mi][nj] = __builtin_amdgcn_mfma_f32_16x16x32_bf16(af[mi], bfr[nj], acc[mi][nj], 0,0,0);
    __syncthreads();
  }
  // dump accumulators to LDS (C/D layout: row=quad*4+reg, col=lane&15), packed converts
  #pragma unroll
  for (int mi=0;mi<4;mi++)
    #pragma unroll
    for (int nj=0;nj<4;nj++){
      union { __hip_bfloat162 h2; u16 u[2]; } cv0, cv1;
      cv0.h2 = __float22bfloat162_rn(make_float2(acc[mi][nj][0], acc[mi][nj][1]));
      cv1.h2 = __float22bfloat162_rn(make_float2(acc[mi][nj][2], acc[mi][nj][3]));
      int col = w*64 + nj*16 + ln;
      int rbase = mi*16 + quad*4;
      sh[(rbase+0)*264 + col] = cv0.u[0];
      sh[(rbase+1)*264 + col] = cv0.u[1];
      sh[(rbase+2)*264 + col] = cv1.u[0];
      sh[(rbase+3)*264 + col] = cv1.u[1];
    }
  __syncthreads();
  // coalesced bulk store of the 64x256 bf16 tile
  #pragma unroll
  for (int j=0;j<8;j++){
    int idx = j*256 + tid;
    int r = idx >> 5, gq = idx & 31;
    if (m0 + r < M)
      *(uint4*)(C + (size_t)(m0+r)*HC + gq*8) = *(const uint4*)&sh[r*264 + gq*8];
  }
  // per-row attention dots, shuffle-free: lane l -> row w*16+(l&15), head l>>4.
  {
    int r  = w*16 + ln;
    int hh = quad;
    const u16* crow = &sh[r*264 + hh*64];
    const float* asv = &att_sh[hh*64];
    const float* adv = &att_sh[256 + hh*64];
    float ps = 0.f, pd = 0.f;
    #pragma unroll
    for (int cb=0; cb<64; cb+=8){
      ushort4 ua = *(const ushort4*)&crow[cb];
      ushort4 ub = *(const ushort4*)&crow[cb+4];
      float4 sa = *(const float4*)&asv[cb];
      float4 sb = *(const float4*)&asv[cb+4];
      float4 da = *(const float4*)&adv[cb];
      float4 db = *(const float4*)&adv[cb+4];
      float c0=b2f(ua.x), c1=b2f(ua.y), c2=b2f(ua.z), c3=b2f(ua.w);
      float c4=b2f(ub.x), c5=b2f(ub.y), c6=b2f(ub.z), c7=b2f(ub.w);
      ps += c0*sa.x + c1*sa.y + c2*sa.z + c3*sa.w + c4*sb.x + c5*sb.y + c6*sb.z + c7*sb.w;
      pd += c0*da.x + c1*da.y + c2*da.z + c3*da.w + c4*db.x + c5*db.y + c6*db.z + c7*db.w;
    }
    if (m0 + r < M){
      a_s[(size_t)(m0+r)*4 + hh] = ps;
      a_d[(size_t)(m0+r)*4 + hh] = pd;
    }
  }
}

// ---------------- fused segment softmax + aggregation + layer epilogue ----------------
// one wave per destination node, zero LDS. deg<=64: lane p owns edge p; weights are
// pre-transposed into tw[]; inner accumulate in float2 vectors (v_pk_fma_f32).
__global__ __launch_bounds__(256) void k_soft_agg(
    const u16* __restrict__ xs, const int* __restrict__ rowptr, const int* __restrict__ bsums,
    const int* __restrict__ deg, const u64* __restrict__ epk,
    const float* __restrict__ a_s, const float* __restrict__ a_d, const float* __restrict__ ce4,
    const void* __restrict__ bias, void* __restrict__ outp, int N, int layer,
    const int* __restrict__ flagp){
  int bf = *flagp;
  int lane = threadIdx.x & 63;
  int w = threadIdx.x >> 6;
  int n = (blockIdx.x<<2) + w;
  if (n >= N) return;
  int row = rowptr[n] + bsums[n>>8];
  int dg = deg[n];
  float4 ad = *(const float4*)&a_d[(size_t)n*4];
  float4 ce = *(const float4*)ce4;
  int h = lane >> 4;
  float4 acc = make_float4(0.f,0.f,0.f,0.f);
  if (dg > 0){
    if (dg <= 64){
      // --- softmax state fully in registers: lane p owns edge p ---
      int   s_reg = 0;
      float4 ar = make_float4(-1e30f,-1e30f,-1e30f,-1e30f);
      if (lane < dg){
        u64 pk = epk[row + lane];
        int s = (int)(unsigned)(pk & 0xFFFFFFFFull);
        if ((unsigned)s >= (unsigned)N) s = 0;
        s_reg = s;
        float wv = __uint_as_float((unsigned)(pk >> 32));
        float4 as = *(const float4*)&a_s[(size_t)s*4];
        ar.x = lrelu(as.x+ad.x+wv*ce.x);
        ar.y = lrelu(as.y+ad.y+wv*ce.y);
        ar.z = lrelu(as.z+ad.z+wv*ce.z);
        ar.w = lrelu(as.w+ad.w+wv*ce.w);
      }
      float4 m = wave_max4(ar);
      float4 ex = make_float4(0.f,0.f,0.f,0.f);
      if (lane < dg){
        ex.x=__expf(ar.x-m.x); ex.y=__expf(ar.y-m.y);
        ex.z=__expf(ar.z-m.z); ex.w=__expf(ar.w-m.w);
      }
      float4 ss = wave_sum4(ex);
      float4 wgt;
      wgt.x = ex.x/(ss.x+1e-16f); wgt.y = ex.y/(ss.y+1e-16f);
      wgt.z = ex.z/(ss.z+1e-16f); wgt.w = ex.w/(ss.w+1e-16f);
      // --- transpose weights: tw[j] lane l = head-(l>>4) weight of edge j*16+(l&15) ---
      float tw[4];
      #pragma unroll
      for (int j=0;j<4;j++){
        if (j*16 < dg){
          int srcl = j*16 + (lane & 15);
          float c0=__shfl(wgt.x,srcl), c1=__shfl(wgt.y,srcl);
          float c2=__shfl(wgt.z,srcl), c3=__shfl(wgt.w,srcl);
          tw[j] = (h==0)?c0:((h==1)?c1:((h==2)?c2:c3));
        } else tw[j] = 0.f;
      }
      int ibase = lane & 48;   // h*16
      v2f a01 = {0.f,0.f}, a23 = {0.f,0.f};
      // --- aggregation: 16-edge segments, unroll 4; 1 readlane + 1 shfl per edge ---
      #pragma unroll
      for (int j=0;j<4;j++){
        int j0 = j*16;
        if (j0 >= dg) break;
        float twj = tw[j];
        int cnt = dg - j0; if (cnt > 16) cnt = 16;
        int t = 0;
        for (; t+4<=cnt; t+=4){
          int e = j0 + t;
          int s0=__builtin_amdgcn_readlane(s_reg,e+0);
          int s1=__builtin_amdgcn_readlane(s_reg,e+1);
          int s2=__builtin_amdgcn_readlane(s_reg,e+2);
          int s3=__builtin_amdgcn_readlane(s_reg,e+3);
          float w0=__shfl(twj, ibase+t+0);
          float w1=__shfl(twj, ibase+t+1);
          float w2=__shfl(twj, ibase+t+2);
          float w3=__shfl(twj, ibase+t+3);
          uint2 x0 = *(const uint2*)&xs[(size_t)s0*HC + lane*4];
          uint2 x1 = *(const uint2*)&xs[(size_t)s1*HC + lane*4];
          uint2 x2 = *(const uint2*)&xs[(size_t)s2*HC + lane*4];
          uint2 x3 = *(const uint2*)&xs[(size_t)s3*HC + lane*4];
          v2f f;
          f = (v2f){__uint_as_float(x0.x<<16), __uint_as_float(x0.x&0xFFFF0000u)}; a01 += f*w0;
          f = (v2f){__uint_as_float(x0.y<<16), __uint_as_float(x0.y&0xFFFF0000u)}; a23 += f*w0;
          f = (v2f){__uint_as_float(x1.x<<16), __uint_as_float(x1.x&0xFFFF0000u)}; a01 += f*w1;
          f = (v2f){__uint_as_float(x1.y<<16), __uint_as_float(x1.y&0xFFFF0000u)}; a23 += f*w1;
          f = (v2f){__uint_as_float(x2.x<<16), __uint_as_float(x2.x&0xFFFF0000u)}; a01 += f*w2;
          f = (v2f){__uint_as_float(x2.y<<16), __uint_as_float(x2.y&0xFFFF0000u)}; a23 += f*w2;
          f = (v2f){__uint_as_float(x3.x<<16), __uint_as_float(x3.x&0xFFFF0000u)}; a01 += f*w3;
          f = (v2f){__uint_as_float(x3.y<<16), __uint_as_float(x3.y&0xFFFF0000u)}; a23 += f*w3;
        }
        for (; t<cnt; t++){
          int s0=__builtin_amdgcn_readlane(s_reg,j0+t);
          float w0=__shfl(twj, ibase+t);
          uint2 x0 = *(const uint2*)&xs[(size_t)s0*HC + lane*4];
          v2f f;
          f = (v2f){__uint_as_float(x0.x<<16), __uint_as_float(x0.x&0xFFFF0000u)}; a01 += f*w0;
          f = (v2f){__uint_as_float(x0.y<<16), __uint_as_float(x0.y&0xFFFF0000u)}; a23 += f*w0;
        }
      }
      acc.x = a01.x; acc.y = a01.y; acc.z = a23.x; acc.w = a23.y;
    } else {
      // fallback: recompute (no LDS); statistically never taken at E/N=16
      float4 m = make_float4(-1e30f,-1e30f,-1e30f,-1e30f);
      for (int p=lane;p<dg;p+=64){
        u64 pk = epk[row+p];
        int s = (int)(unsigned)(pk & 0xFFFFFFFFull);
        if ((unsigned)s >= (unsigned)N) s = 0;
        float wv = __uint_as_float((unsigned)(pk >> 32));
        float4 as = *(const float4*)&a_s[(size_t)s*4];
        m.x=fmaxf(m.x, lrelu(as.x+ad.x+wv*ce.x));
        m.y=fmaxf(m.y, lrelu(as.y+ad.y+wv*ce.y));
        m.z=fmaxf(m.z, lrelu(as.z+ad.z+wv*ce.z));
        m.w=fmaxf(m.w, lrelu(as.w+ad.w+wv*ce.w));
      }
      m = wave_max4(m);
      float4 ss = make_float4(0.f,0.f,0.f,0.f);
      for (int p=lane;p<dg;p+=64){
        u64 pk = epk[row+p];
        int s = (int)(unsigned)(pk & 0xFFFFFFFFull);
        if ((unsigned)s >= (unsigned)N) s = 0;
        float wv = __uint_as_float((unsigned)(pk >> 32));
        float4 as = *(const float4*)&a_s[(size_t)s*4];
        ss.x+=__expf(lrelu(as.x+ad.x+wv*ce.x)-m.x);
        ss.y+=__expf(lrelu(as.y+ad.y+wv*ce.y)-m.y);
        ss.z+=__expf(lrelu(as.z+ad.z+wv*ce.z)-m.z);
        ss.w+=__expf(lrelu(as.w+ad.w+wv*ce.w)-m.w);
      }
      ss = wave_sum4(ss);
      float rsel=1.f/(sel4(ss,h)+1e-16f), mh=sel4(m,h), adh=sel4(ad,h), ceh=sel4(ce,h);
      for (int e=0;e<dg;e++){
        u64 pk = epk[row+e];
        int s = (int)(unsigned)(pk & 0xFFFFFFFFull);
        if ((unsigned)s >= (unsigned)N) s = 0;
        float wv = __uint_as_float((unsigned)(pk >> 32));
        float arv = lrelu(a_s[(size_t)s*4+h]+adh+wv*ceh);
        float wgt = __expf(arv-mh)*rsel;
        ushort4 xv4 = *(const ushort4*)&xs[(size_t)s*HC + lane*4];
        acc.x+=wgt*b2f(xv4.x); acc.y+=wgt*b2f(xv4.y);
        acc.z+=wgt*b2f(xv4.z); acc.w+=wgt*b2f(xv4.w);
      }
    }
  }
  if (layer==1){
    // h = relu(l2norm(acc + b1)) -> bf16
    float4 v;
    v.x = acc.x + ldf(bias, lane*4+0, bf);
    v.y = acc.y + ldf(bias, lane*4+1, bf);
    v.z = acc.z + ldf(bias, lane*4+2, bf);
    v.w = acc.w + ldf(bias, lane*4+3, bf);
    float ss = v.x*v.x+v.y*v.y+v.z*v.z+v.w*v.w;
    #pragma unroll
    for(int o=32;o>0;o>>=1) ss += __shfl_xor(ss,o);
    float inv = 1.f/fmaxf(sqrtf(ss), 1e-12f);
    ushort4 o4;
    o4.x = f2b(fmaxf(v.x*inv,0.f)); o4.y = f2b(fmaxf(v.y*inv,0.f));
    o4.z = f2b(fmaxf(v.z*inv,0.f)); o4.w = f2b(fmaxf(v.w*inv,0.f));
    *(ushort4*)((u16*)outp + (size_t)n*HC + lane*4) = o4;
  } else {
    // mean over heads + b2 -> final output
    float4 s = acc;
    #pragma unroll
    for (int o=16;o<=32;o<<=1){
      s.x+=__shfl_xor(s.x,o); s.y+=__shfl_xor(s.y,o);
      s.z+=__shfl_xor(s.z,o); s.w+=__shfl_xor(s.w,o);
    }
    if (lane < 16){
      float4 v;
      v.x = 0.25f*s.x + ldf(bias, lane*4+0, bf);
      v.y = 0.25f*s.y + ldf(bias, lane*4+1, bf);
      v.z = 0.25f*s.z + ldf(bias, lane*4+2, bf);
      v.w = 0.25f*s.w + ldf(bias, lane*4+3, bf);
      if (bf){
        ushort4 o4; o4.x=f2b(v.x); o4.y=f2b(v.y); o4.z=f2b(v.z); o4.w=f2b(v.w);
        *(ushort4*)((u16*)outp + (size_t)n*CDIM + lane*4) = o4;
      } else {
        *(float4*)((float*)outp + (size_t)n*CDIM + lane*4) = v;
      }
    }
  }
}

extern "C" void kernel_launch(void* const* d_in, const int* in_sizes, int n_in,
                              void* d_out, int out_size, void* d_ws, size_t ws_size,
                              hipStream_t stream){
  const void* x_in = d_in[0];
  const int* eidx  = (const int*)d_in[1];
  const void* ew   = d_in[2];
  const void* W1   = d_in[3];
  const void* as1  = d_in[4];
  const void* ad1  = d_in[5];
  const void* We1  = d_in[6];
  const void* ae1  = d_in[7];
  const void* b1   = d_in[8];
  const void* W2   = d_in[9];
  const void* as2  = d_in[10];
  const void* ad2  = d_in[11];
  const void* We2  = d_in[12];
  const void* ae2  = d_in[13];
  const void* b2   = d_in[14];

  int N = in_sizes[0]/128;
  int E = in_sizes[2];
  const int* src = eidx;
  const int* dst = eidx + E;

  char* w = (char*)d_ws;
  auto alloc = [&](size_t bytes)->char*{ char* p=w; w += (bytes+255)/256*256; return p; };
  int*   flag  = (int*)alloc(256);
  u16*   xs    = (u16*)alloc((size_t)N*HC*2);   // bf16 feature buffer A
  u16*   agg   = (u16*)alloc((size_t)N*HC*2);   // bf16 feature buffer B (h); GEMM2 tail over-reads into a_s (safe)
  float* a_s   = (float*)alloc((size_t)N*4*4);
  float* a_d   = (float*)alloc((size_t)N*4*4);
  int*   deg   = (int*)alloc((size_t)N*4);
  int*   rowptr= (int*)alloc((size_t)N*4);
  int*   bsums = (int*)alloc(256*4);
  int*   rank  = (int*)alloc((size_t)E*4);      // per-edge rank within dst bucket
  u64*   epk   = (u64*)alloc((size_t)E*8);      // packed (ew<<32 | src) per edge
  float* ce    = (float*)alloc(256);            // [0:4)=layer1, [4:8)=layer2
  u16*   Bt1   = (u16*)alloc((size_t)HC*128*2); // W1^T bf16 [256][128]
  u16*   Bt2   = (u16*)alloc((size_t)HC*HC*2);  // W2^T bf16 [256][256]

  (void)hipMemsetAsync(deg, 0, (size_t)N*4, stream);

  int eb = (E+255)/256;
  int nb = (N+255)/256;
  k_hist<<<eb,256,0,stream>>>(dst, E, N, deg, rank, (const u16*)x_in, in_sizes[0], flag);
  k_scan1<<<nb,256,0,stream>>>(deg, rowptr, bsums, N);
  k_scan2<<<1,256,0,stream>>>(bsums, nb);
  k_scatter<<<eb,256,0,stream>>>(src, dst, ew, E, N, rowptr, bsums, rank, epk, flag);
  k_prep<<<385,256,0,stream>>>(W1, W2, We1, ae1, We2, ae2, Bt1, Bt2, ce, flag);

  int gemmBlocks = (N+63)/64;
  int nwb = (N+3)/4;   // 4 node-waves per block

  // ---- layer 1 ----
  k_gemm_mfma<<<gemmBlocks,256,0,stream>>>(x_in, 1, Bt1, xs, as1, ad1, a_s, a_d, N, 128, flag);
  k_soft_agg<<<nwb,256,0,stream>>>(xs, rowptr, bsums, deg, epk, a_s, a_d, ce, b1, agg, N, 1, flag);

  // ---- layer 2 ----
  k_gemm_mfma<<<gemmBlocks,256,0,stream>>>(agg, 0, Bt2, xs, as2, ad2, a_s, a_d, N, 256, flag);
  k_soft_agg<<<nwb,256,0,stream>>>(xs, rowptr, bsums, deg, epk, a_s, a_d, ce+4, b2, d_out, N, 2, flag);
}